// Round 3
// baseline (434.137 us; speedup 1.0000x reference)
//
#include <hip/hip_runtime.h>
#include <hip/hip_bf16.h>

// B=8, S=2048, DMODEL=1024, DK=128
typedef __bf16 bf16x8 __attribute__((ext_vector_type(8)));
typedef float  f32x4  __attribute__((ext_vector_type(4)));

// ---------------- workspace layout (bf16 elements) ----------------
// wpackF: [3][hi/lo][131072] fragment-ordered W        = 0 .. 786432
// q:      [16384][128] row-major                        at 786432
// kpack:  [256 tiles][1024 chunks][8] fragment-ordered  at 2883584
// vpack:  [256 tiles][1024 chunks][8] fragment-ordered  at 4980736
// fp32 K-split partials after 14155776 bytes
#define WS_Q  786432
#define WS_KP 2883584
#define WS_VP 4980736
#define WS_BF16_BYTES 14155776ull

// ---------------------------------------------------------------------------
// Kernel 1: Wq/Wk/Wv fp32 -> split bf16 (hi+lo) in MFMA B-fragment order.
// Fragment chunk c = ((kk*2+ks)*8+nt)*64 + lane ; element j in [0,8).
// Source: col = nt*16 + (lane&15), k = kk*64 + ks*32 + (lane>>4)*8 + j.
// Scale 1/sqrt(128) * log2(e) folded into Wq (softmax done in log2 domain).
// ---------------------------------------------------------------------------
__global__ __launch_bounds__(256) void wconv_kernel(
    const float* __restrict__ wq, const float* __restrict__ wk,
    const float* __restrict__ wv, __bf16* __restrict__ wpack)
{
    int i = blockIdx.x * 256 + threadIdx.x;     // 0 .. 393215
    int p = i >> 17, o = i & 131071;
    int c = o >> 3, j = o & 7;
    int l15 = c & 15, g = (c >> 4) & 3, nt = (c >> 6) & 7, ks = (c >> 9) & 1, kk = c >> 10;
    int col = nt * 16 + l15;
    int k = kk * 64 + ks * 32 + g * 8 + j;
    const float* src = (p == 0) ? wq : ((p == 1) ? wk : wv);
    float f = src[col * 1024 + k];
    if (p == 0) f *= (0.08838834764831845f * 1.44269504088896340736f);
    __bf16 h = (__bf16)f;
    __bf16 l = (__bf16)(f - (float)h);
    wpack[p * 262144 + o]          = h;
    wpack[p * 262144 + 131072 + o] = l;
}

// ---------------------------------------------------------------------------
// Kernel 2: projection GEMM, NO LDS staging, NO main-loop barriers.
// Block: 64 rows x 128 cols, 4 waves x 16 rows. grid (256, 3) = 768 blocks.
// A (x) frags: direct global f32x4 loads + cvt. B (W) frags: coalesced 16B
// loads from fragment-ordered wpackF (L2-resident). acc += xh*wh + xh*wl.
// Epilogue: C->LDS transpose, then store q row-major / k,v fragment-packed.
// ---------------------------------------------------------------------------
__global__ __launch_bounds__(256, 4) void proj_kernel(
    const float* __restrict__ xq, const float* __restrict__ xk,
    const float* __restrict__ xv, const __bf16* __restrict__ wpack,
    __bf16* __restrict__ qws, __bf16* __restrict__ kpack, __bf16* __restrict__ vpack)
{
    const int p = blockIdx.y;
    const float* __restrict__ x = (p == 0) ? xq : ((p == 1) ? xk : xv);
    const __bf16* __restrict__ wf = wpack + p * 262144;   // hi plane; lo = +131072

    const int mtile = blockIdx.x;               // [0,256)
    const int m0 = mtile << 6;
    const int t = threadIdx.x;
    const int wv_ = t >> 6;
    const int lane = t & 63;
    const int l15 = lane & 15, g = lane >> 4;

    __shared__ __align__(16) __bf16 olds[9216];  // epilogue transpose buffer

    f32x4 acc[8];
#pragma unroll
    for (int nt = 0; nt < 8; ++nt) acc[nt] = (f32x4){0.f, 0.f, 0.f, 0.f};

    const float* xrow = x + (size_t)(m0 + wv_ * 16 + l15) * 1024 + g * 8;

    // preload kk=0 x fragments (raw fp32)
    f32x4 a0 = *(const f32x4*)(xrow);
    f32x4 a1 = *(const f32x4*)(xrow + 4);
    f32x4 b0 = *(const f32x4*)(xrow + 32);
    f32x4 b1 = *(const f32x4*)(xrow + 36);

    for (int kk = 0; kk < 16; ++kk) {
        // prefetch next iteration's x fragments
        f32x4 na0, na1, nb0, nb1;
        if (kk < 15) {
            const float* nx = xrow + (kk + 1) * 64;
            na0 = *(const f32x4*)(nx);
            na1 = *(const f32x4*)(nx + 4);
            nb0 = *(const f32x4*)(nx + 32);
            nb1 = *(const f32x4*)(nx + 36);
        }
        bf16x8 ah0, ah1;
#pragma unroll
        for (int j = 0; j < 4; ++j) {
            ah0[j] = (__bf16)a0[j]; ah0[4 + j] = (__bf16)a1[j];
            ah1[j] = (__bf16)b0[j]; ah1[4 + j] = (__bf16)b1[j];
        }
        const __bf16* wb = wf + kk * 8192 + lane * 8;
#pragma unroll
        for (int nt = 0; nt < 8; ++nt) {
            bf16x8 bh0 = *(const bf16x8*)(wb + nt * 512);
            bf16x8 bl0 = *(const bf16x8*)(wb + nt * 512 + 131072);
            bf16x8 bh1 = *(const bf16x8*)(wb + nt * 512 + 4096);
            bf16x8 bl1 = *(const bf16x8*)(wb + nt * 512 + 4096 + 131072);
            acc[nt] = __builtin_amdgcn_mfma_f32_16x16x32_bf16(ah0, bh0, acc[nt], 0, 0, 0);
            acc[nt] = __builtin_amdgcn_mfma_f32_16x16x32_bf16(ah0, bl0, acc[nt], 0, 0, 0);
            acc[nt] = __builtin_amdgcn_mfma_f32_16x16x32_bf16(ah1, bh1, acc[nt], 0, 0, 0);
            acc[nt] = __builtin_amdgcn_mfma_f32_16x16x32_bf16(ah1, bl1, acc[nt], 0, 0, 0);
        }
        a0 = na0; a1 = na1; b0 = nb0; b1 = nb1;
    }

    // ---- epilogue: C frags -> LDS (q,k: [64][136]; v: transposed [128][72])
#pragma unroll
    for (int nt = 0; nt < 8; ++nt)
#pragma unroll
        for (int r = 0; r < 4; ++r) {
            int rowl = wv_ * 16 + g * 4 + r;    // C row = (lane>>4)*4 + reg
            int col = nt * 16 + l15;            // C col = lane&15
            __bf16 v = (__bf16)acc[nt][r];
            if (p < 2) olds[rowl * 136 + col] = v;
            else       olds[col * 72 + rowl] = v;
        }
    __syncthreads();

    if (p == 0) {
        // q row-major [s][128]
#pragma unroll
        for (int i = 0; i < 4; ++i) {
            int idx = i * 256 + t;
            int row = idx >> 4, ck = idx & 15;
            bf16x8 v = *(const bf16x8*)(olds + row * 136 + ck * 8);
            *(bf16x8*)(qws + (size_t)(m0 + row) * 128 + ck * 8) = v;
        }
    } else if (p == 1) {
        // kpack: chunk idx = (ks*4+nt)*64 + lane'; elem j = K[nt*16+l'][ks*32+g'*8+j]
#pragma unroll
        for (int i = 0; i < 4; ++i) {
            int idx = i * 256 + t;
            int ks = idx >> 8, nt = (idx >> 6) & 3, ln = idx & 63;
            int gg = ln >> 4, ll = ln & 15;
            bf16x8 v = *(const bf16x8*)(olds + (nt * 16 + ll) * 136 + ks * 32 + gg * 8);
            *(bf16x8*)(kpack + ((size_t)mtile * 1024 + idx) * 8) = v;
        }
    } else {
        // vpack: chunk idx = (ks2*8+nt2)*64 + lane'; elem j = V[ks2*32+g'*8+j][nt2*16+l']
#pragma unroll
        for (int i = 0; i < 4; ++i) {
            int idx = i * 256 + t;
            int ks2 = idx >> 9, nt2 = (idx >> 6) & 7, ln = idx & 63;
            int gg = ln >> 4, ll = ln & 15;
            bf16x8 v = *(const bf16x8*)(olds + (nt2 * 16 + ll) * 72 + ks2 * 32 + gg * 8);
            *(bf16x8*)(vpack + ((size_t)mtile * 1024 + idx) * 8) = v;
        }
    }
}

// ---------------------------------------------------------------------------
// Kernel 3: flash attention, NO barriers. BLOCK_M=64 (4 waves x 16 rows),
// BLOCK_N=64. K/V B-fragments read directly from fragment-packed global
// (per-XCD L2 resident: bb = blockIdx&7). Only LDS: wave-private P transform.
// Softmax in log2 domain (L2E folded into Wq).
// ---------------------------------------------------------------------------
__global__ __launch_bounds__(256, 3) void flash_kernel(
    const __bf16* __restrict__ qws, const __bf16* __restrict__ kpack,
    const __bf16* __restrict__ vpack, const int* __restrict__ mask,
    float* __restrict__ out, float* __restrict__ part, float* __restrict__ mlbuf,
    int ktp)
{
    const int bb = blockIdx.x & 7;
    const int rest = blockIdx.x >> 3;
    const int mtile = rest & 31;
    const int jsplit = rest >> 5;
    const int sq0 = mtile << 6;
    const int t = threadIdx.x;
    const int wv_ = t >> 6;
    const int lane = t & 63;
    const int l15 = lane & 15, g = lane >> 4;

    // wave-private P buffer: 16 rows x stride 72 (2-way-only conflicts, 16B aligned)
    __shared__ __align__(16) __bf16 psmem[4 * 1152];
    __bf16* plds = psmem + wv_ * 1152;

    // Q fragments (A-layout, pre-scaled by L2E/sqrt(dk) via Wq)
    bf16x8 qf[4];
    {
        const __bf16* qp = qws + ((size_t)(bb * 2048 + sq0 + wv_ * 16 + l15)) * 128 + g * 8;
#pragma unroll
        for (int ks = 0; ks < 4; ++ks) qf[ks] = *(const bf16x8*)(qp + ks * 32);
    }

    f32x4 o[8];
#pragma unroll
    for (int nt = 0; nt < 8; ++nt) o[nt] = (f32x4){0.f, 0.f, 0.f, 0.f};
    float m_run[4], l_run[4];
#pragma unroll
    for (int r = 0; r < 4; ++r) { m_run[r] = -__builtin_inff(); l_run[r] = 0.f; }

    const int* mbase = mask + ((size_t)(bb * 2048 + sq0 + wv_ * 16 + g * 4)) * 2048 + l15;
    const __bf16* kbase = kpack + ((size_t)(bb * 32) * 1024) * 8 + lane * 8;
    const __bf16* vbase = vpack + ((size_t)(bb * 32) * 1024) * 8 + lane * 8;

    const int kt_begin = jsplit * ktp, kt_end = kt_begin + ktp;
    for (int kt = kt_begin; kt < kt_end; ++kt) {
        const int n0 = kt << 6;

        // mask values (scattered int loads, hoistable by scheduler)
        int mv[4][4];
#pragma unroll
        for (int nt = 0; nt < 4; ++nt)
#pragma unroll
            for (int r = 0; r < 4; ++r)
                mv[nt][r] = mbase[(size_t)r * 2048 + n0 + nt * 16];

        // S = Q K^T  (log2-domain, pre-scaled)
        const __bf16* kb = kbase + kt * 8192;
        f32x4 sf[4];
#pragma unroll
        for (int nt = 0; nt < 4; ++nt) sf[nt] = (f32x4){0.f, 0.f, 0.f, 0.f};
#pragma unroll
        for (int nt = 0; nt < 4; ++nt)
#pragma unroll
            for (int ks = 0; ks < 4; ++ks) {
                bf16x8 bfk = *(const bf16x8*)(kb + (ks * 4 + nt) * 512);
                sf[nt] = __builtin_amdgcn_mfma_f32_16x16x32_bf16(qf[ks], bfk, sf[nt], 0, 0, 0);
            }

        // online softmax (rows g*4+r; reduce across 16 l15 lanes)
        float mx[4], mnew[4], alpha[4], psum[4];
#pragma unroll
        for (int r = 0; r < 4; ++r)
            mx[r] = fmaxf(fmaxf(sf[0][r], sf[1][r]), fmaxf(sf[2][r], sf[3][r]));
#pragma unroll
        for (int off = 1; off < 16; off <<= 1)
#pragma unroll
            for (int r = 0; r < 4; ++r)
                mx[r] = fmaxf(mx[r], __shfl_xor(mx[r], off, 64));
#pragma unroll
        for (int r = 0; r < 4; ++r) {
            mnew[r] = fmaxf(m_run[r], mx[r]);       // unmasked max: always finite
            alpha[r] = exp2f(m_run[r] - mnew[r]);
            psum[r] = 0.f;
        }
#pragma unroll
        for (int nt = 0; nt < 4; ++nt)
#pragma unroll
            for (int r = 0; r < 4; ++r) {
                float pv = exp2f(sf[nt][r] - mnew[r]);
                pv = mv[nt][r] ? pv : 0.f;          // mask after exp: exact
                psum[r] += pv;
                plds[(g * 4 + r) * 72 + nt * 16 + l15] = (__bf16)pv;
            }
#pragma unroll
        for (int off = 1; off < 16; off <<= 1)
#pragma unroll
            for (int r = 0; r < 4; ++r)
                psum[r] += __shfl_xor(psum[r], off, 64);
#pragma unroll
        for (int r = 0; r < 4; ++r) {
            l_run[r] = l_run[r] * alpha[r] + psum[r];
            m_run[r] = mnew[r];
        }
#pragma unroll
        for (int nt = 0; nt < 8; ++nt)
#pragma unroll
            for (int r = 0; r < 4; ++r) o[nt][r] *= alpha[r];

        // P: C-layout -> A-layout via wave-private LDS (in-wave waitcnt only)
        bf16x8 pa[2];
#pragma unroll
        for (int ks2 = 0; ks2 < 2; ++ks2)
            pa[ks2] = *(const bf16x8*)(plds + l15 * 72 + ks2 * 32 + g * 8);

        // O += P V
        const __bf16* vb = vbase + kt * 8192;
#pragma unroll
        for (int nt2 = 0; nt2 < 8; ++nt2)
#pragma unroll
            for (int ks2 = 0; ks2 < 2; ++ks2) {
                bf16x8 bfv = *(const bf16x8*)(vb + (ks2 * 8 + nt2) * 512);
                o[nt2] = __builtin_amdgcn_mfma_f32_16x16x32_bf16(pa[ks2], bfv, o[nt2], 0, 0, 0);
            }
    }

    if (part == nullptr) {
        float inv[4];
#pragma unroll
        for (int r = 0; r < 4; ++r) inv[r] = 1.0f / l_run[r];
#pragma unroll
        for (int nt2 = 0; nt2 < 8; ++nt2)
#pragma unroll
            for (int r = 0; r < 4; ++r)
                out[((size_t)(bb * 2048 + sq0 + wv_ * 16 + g * 4 + r)) * 128 + nt2 * 16 + l15] =
                    o[nt2][r] * inv[r];
    } else {
#pragma unroll
        for (int nt2 = 0; nt2 < 8; ++nt2)
#pragma unroll
            for (int r = 0; r < 4; ++r) {
                size_t rowg = (size_t)(bb * 2048 + sq0 + wv_ * 16 + g * 4 + r);
                part[((size_t)jsplit * 16384 + rowg) * 128 + nt2 * 16 + l15] = o[nt2][r];
            }
        if (l15 == 0) {
#pragma unroll
            for (int r = 0; r < 4; ++r) {
                size_t rowg = (size_t)(bb * 2048 + sq0 + wv_ * 16 + g * 4 + r);
                mlbuf[((size_t)jsplit * 16384 + rowg) * 2]     = m_run[r];
                mlbuf[((size_t)jsplit * 16384 + rowg) * 2 + 1] = l_run[r];
            }
        }
    }
}

// ---------------------------------------------------------------------------
// Kernel 4: merge K-split partials (log2-domain m).
// ---------------------------------------------------------------------------
__global__ __launch_bounds__(256) void merge_kernel(
    const float* __restrict__ part, const float* __restrict__ mlbuf,
    float* __restrict__ out, int J)
{
    int t = threadIdx.x;
    size_t row = (size_t)blockIdx.x * 8 + (t >> 5);
    int c = (t & 31) * 4;
    float mj[4];
    float m = -__builtin_inff();
    for (int j = 0; j < J; ++j) {
        mj[j] = mlbuf[((size_t)j * 16384 + row) * 2];
        m = fmaxf(m, mj[j]);
    }
    float l = 0.f;
    f32x4 acc = (f32x4){0.f, 0.f, 0.f, 0.f};
    for (int j = 0; j < J; ++j) {
        float w = exp2f(mj[j] - m);
        l += w * mlbuf[((size_t)j * 16384 + row) * 2 + 1];
        f32x4 v = *(const f32x4*)(part + ((size_t)j * 16384 + row) * 128 + c);
#pragma unroll
        for (int e = 0; e < 4; ++e) acc[e] += w * v[e];
    }
    float inv = 1.0f / l;
#pragma unroll
    for (int e = 0; e < 4; ++e) acc[e] *= inv;
    *(f32x4*)(out + row * 128 + c) = acc;
}

// ---------------------------------------------------------------------------
extern "C" void kernel_launch(void* const* d_in, const int* in_sizes, int n_in,
                              void* d_out, int out_size, void* d_ws, size_t ws_size,
                              hipStream_t stream)
{
    const float* query = (const float*)d_in[0];
    const float* key   = (const float*)d_in[1];
    const float* value = (const float*)d_in[2];
    const int*   mask  = (const int*)d_in[3];
    const float* Wq    = (const float*)d_in[4];
    const float* Wk    = (const float*)d_in[5];
    const float* Wv    = (const float*)d_in[6];
    float* out = (float*)d_out;

    __bf16* wpack = (__bf16*)d_ws;
    __bf16* qws = wpack + WS_Q;
    __bf16* kpack = wpack + WS_KP;
    __bf16* vpack = wpack + WS_VP;

    // K-split from workspace budget: per split 16384*128*4 + 16384*8 bytes
    const size_t per_split = 16384ull * 128 * 4 + 16384ull * 8;
    int J = 1;
    if (ws_size >= WS_BF16_BYTES + 4 * per_split)      J = 4;
    else if (ws_size >= WS_BF16_BYTES + 2 * per_split) J = 2;
    float* part = (J > 1) ? (float*)((char*)d_ws + WS_BF16_BYTES) : nullptr;
    float* mlbuf = (J > 1) ? (part + (size_t)J * 16384 * 128) : nullptr;

    wconv_kernel<<<1536, 256, 0, stream>>>(Wq, Wk, Wv, wpack);
    proj_kernel<<<dim3(256, 3), 256, 0, stream>>>(query, key, value, wpack, qws, kpack, vpack);
    flash_kernel<<<256 * J, 256, 0, stream>>>(qws, kpack, vpack, mask, out, part, mlbuf, 32 / J);
    if (J > 1) merge_kernel<<<2048, 256, 0, stream>>>(part, mlbuf, out, J);
}